// Round 9
// baseline (454.258 us; speedup 1.0000x reference)
//
#include <hip/hip_runtime.h>
#include <hip/hip_bf16.h>
#include <math.h>

#define B_  4
#define L_  2048
#define D_  1024
#define H_  16
#define HS_ 64
#define SCALE 0.125f   // 1/sqrt(64)
#define SCALE2 0.18033688011112042f  // 0.125 * log2(e): softmax in exp2 domain

typedef unsigned short ushort_t;
typedef __attribute__((ext_vector_type(8))) short short8;
typedef __attribute__((ext_vector_type(4))) float f32x4;

#define MFMA __builtin_amdgcn_mfma_f32_16x16x32_bf16

static __device__ __forceinline__ ushort_t f2bf(float f) {
    union { float f; unsigned int u; } cv; cv.f = f;
    unsigned int u = cv.u;
    unsigned int r = (u + 0x7FFFu + ((u >> 16) & 1u)) >> 16;   // RNE
    return (ushort_t)r;
}
static __device__ __forceinline__ float bf2f(ushort_t h) {
    union { float f; unsigned int u; } cv; cv.u = ((unsigned int)h) << 16;
    return cv.f;
}

static __device__ __forceinline__ void gload_lds16(const ushort_t* g, ushort_t* l) {
    __builtin_amdgcn_global_load_lds(
        (const __attribute__((address_space(1))) unsigned int*)g,
        (__attribute__((address_space(3))) unsigned int*)l, 16, 0, 0);
}

// ---------------------------------------------------------------------------
// Prep kernels: fp32 -> bf16 (x, Er), fp32 -> bf16 transposed (weights)
// ---------------------------------------------------------------------------
__global__ __launch_bounds__(256)
void conv_to_bf16(const float* __restrict__ x, ushort_t* __restrict__ xb)
{
    const size_t i = (size_t)blockIdx.x * 256 + threadIdx.x;   // 8 elems/thread
    const float4* src = (const float4*)x + i * 2;
    float4 a = src[0], b = src[1];
    ushort_t o[8] = {f2bf(a.x), f2bf(a.y), f2bf(a.z), f2bf(a.w),
                     f2bf(b.x), f2bf(b.y), f2bf(b.z), f2bf(b.w)};
    *(uint4*)(xb + i * 8) = *(uint4*)o;
}

__global__ void zero_u32(unsigned int* __restrict__ p) { *p = 0u; }

__global__ __launch_bounds__(256)
void transpose_to_bf16(const float* __restrict__ W, ushort_t* __restrict__ Wt,
                       int K, int N)   // W:[K][N] -> Wt:[N][K]
{
    __shared__ ushort_t tile[64][65];
    const int tid = threadIdx.x;
    const int n0 = blockIdx.x * 64, k0 = blockIdx.y * 64;
#pragma unroll
    for (int s = 0; s < 16; ++s) {
        const int idx = s * 256 + tid;
        const int kl = idx >> 6, nl = idx & 63;
        tile[nl][kl] = f2bf(W[(size_t)(k0 + kl) * N + n0 + nl]);
    }
    __syncthreads();
#pragma unroll
    for (int s = 0; s < 8; ++s) {
        const int idx = s * 256 + tid;
        const int nl = idx >> 5, kc = idx & 31;
        const unsigned int vlo = tile[nl][kc * 2];
        const unsigned int vhi = tile[nl][kc * 2 + 1];
        *(unsigned int*)(Wt + (size_t)(n0 + nl) * K + k0 + kc * 2) =
            vlo | (vhi << 16);
    }
}

// ---------------------------------------------------------------------------
// m97-style bf16 MFMA GEMM: C[M][N] = A[M][K] @ Bt[N][K]^T
// + XCD-bijective block swizzle (grids 1536/512, both %8==0).
// ---------------------------------------------------------------------------
__global__ __launch_bounds__(256)
void qkv_mfma(const ushort_t* __restrict__ A, const ushort_t* __restrict__ Bt,
              const float* __restrict__ bias, ushort_t* __restrict__ qkv)
{
    __shared__ __align__(16) ushort_t As[128 * 64];
    __shared__ __align__(16) ushort_t Bs[128 * 64];

    const int tid = threadIdx.x;
    const int w = tid >> 6, lane = tid & 63, quad = lane >> 4, lcol = lane & 15;
    const int wr = w >> 1, wc = w & 1;
    unsigned wg = blockIdx.y * gridDim.x + blockIdx.x;
    const unsigned nwg = gridDim.x * gridDim.y;
    wg = (wg & 7) * (nwg >> 3) + (wg >> 3);
    const int m0 = (int)(wg / gridDim.x) * 128;
    const int n0 = (int)(wg % gridDim.x) * 128;
    const int K = D_;

    const int srow = tid >> 3;
    const int cg = (tid & 7) ^ (srow & 7);
    const ushort_t* gA = A + (size_t)(m0 + srow) * K + cg * 8;
    const ushort_t* gB = Bt + (size_t)(n0 + srow) * K + cg * 8;
    ushort_t* lA = As + tid * 8;
    ushort_t* lB = Bs + tid * 8;

    const int cs0 = ((quad) ^ (lcol & 7)) * 8;
    const int cs1 = ((4 + quad) ^ (lcol & 7)) * 8;

    f32x4 acc[4][4];
#pragma unroll
    for (int i = 0; i < 4; ++i)
#pragma unroll
        for (int j = 0; j < 4; ++j) acc[i][j] = (f32x4){0, 0, 0, 0};

    for (int k0 = 0; k0 < K; k0 += 64) {
        __syncthreads();
#pragma unroll
        for (int s = 0; s < 4; ++s) {
            gload_lds16(gA + k0 + (size_t)s * 32 * K, lA + s * 2048);
            gload_lds16(gB + k0 + (size_t)s * 32 * K, lB + s * 2048);
        }
        __syncthreads();
#pragma unroll
        for (int kk = 0; kk < 2; ++kk) {
            const int cs = kk ? cs1 : cs0;
            short8 af[4], bf[4];
#pragma unroll
            for (int i = 0; i < 4; ++i)
                af[i] = *(const short8*)&As[(wr * 64 + i * 16 + lcol) * 64 + cs];
#pragma unroll
            for (int j = 0; j < 4; ++j)
                bf[j] = *(const short8*)&Bs[(wc * 64 + j * 16 + lcol) * 64 + cs];
#pragma unroll
            for (int i = 0; i < 4; ++i)
#pragma unroll
                for (int j = 0; j < 4; ++j)
                    acc[i][j] = MFMA(af[i], bf[j], acc[i][j], 0, 0, 0);
        }
    }

    const size_t per = (size_t)B_ * H_ * L_ * HS_;
#pragma unroll
    for (int j = 0; j < 4; ++j) {
        const int col = n0 + wc * 64 + j * 16 + lcol;
        const float bv = bias[col];
        const int sel = col >> 10;
        const int within = col & 1023;
        const int hh = within >> 6, hs = within & 63;
        ushort_t* base = qkv + (size_t)sel * per;
#pragma unroll
        for (int i = 0; i < 4; ++i) {
#pragma unroll
            for (int reg = 0; reg < 4; ++reg) {
                const int row = m0 + wr * 64 + i * 16 + quad * 4 + reg;
                const int bb = row >> 11, ll = row & 2047;
                base[(((size_t)(bb * H_ + hh)) * L_ + ll) * HS_ + hs] =
                    f2bf(acc[i][j][reg] + bv);
            }
        }
    }
}

__global__ __launch_bounds__(256)
void proj_mfma(const ushort_t* __restrict__ A, const ushort_t* __restrict__ Bt,
               const float* __restrict__ bias, float* __restrict__ C)
{
    __shared__ __align__(16) ushort_t As[128 * 64];
    __shared__ __align__(16) ushort_t Bs[128 * 64];

    const int tid = threadIdx.x;
    const int w = tid >> 6, lane = tid & 63, quad = lane >> 4, lcol = lane & 15;
    const int wr = w >> 1, wc = w & 1;
    unsigned wg = blockIdx.y * gridDim.x + blockIdx.x;
    const unsigned nwg = gridDim.x * gridDim.y;
    wg = (wg & 7) * (nwg >> 3) + (wg >> 3);
    const int m0 = (int)(wg / gridDim.x) * 128;
    const int n0 = (int)(wg % gridDim.x) * 128;
    const int K = D_;
    const int N = D_;

    const int srow = tid >> 3;
    const int cg = (tid & 7) ^ (srow & 7);
    const ushort_t* gA = A + (size_t)(m0 + srow) * K + cg * 8;
    const ushort_t* gB = Bt + (size_t)(n0 + srow) * K + cg * 8;
    ushort_t* lA = As + tid * 8;
    ushort_t* lB = Bs + tid * 8;

    const int cs0 = ((quad) ^ (lcol & 7)) * 8;
    const int cs1 = ((4 + quad) ^ (lcol & 7)) * 8;

    f32x4 acc[4][4];
#pragma unroll
    for (int i = 0; i < 4; ++i)
#pragma unroll
        for (int j = 0; j < 4; ++j) acc[i][j] = (f32x4){0, 0, 0, 0};

    for (int k0 = 0; k0 < K; k0 += 64) {
        __syncthreads();
#pragma unroll
        for (int s = 0; s < 4; ++s) {
            gload_lds16(gA + k0 + (size_t)s * 32 * K, lA + s * 2048);
            gload_lds16(gB + k0 + (size_t)s * 32 * K, lB + s * 2048);
        }
        __syncthreads();
#pragma unroll
        for (int kk = 0; kk < 2; ++kk) {
            const int cs = kk ? cs1 : cs0;
            short8 af[4], bf[4];
#pragma unroll
            for (int i = 0; i < 4; ++i)
                af[i] = *(const short8*)&As[(wr * 64 + i * 16 + lcol) * 64 + cs];
#pragma unroll
            for (int j = 0; j < 4; ++j)
                bf[j] = *(const short8*)&Bs[(wc * 64 + j * 16 + lcol) * 64 + cs];
#pragma unroll
            for (int i = 0; i < 4; ++i)
#pragma unroll
                for (int j = 0; j < 4; ++j)
                    acc[i][j] = MFMA(af[i], bf[j], acc[i][j], 0, 0, 0);
        }
    }

#pragma unroll
    for (int j = 0; j < 4; ++j) {
        const int col = n0 + wc * 64 + j * 16 + lcol;
        const float bv = bias[col];
#pragma unroll
        for (int i = 0; i < 4; ++i) {
#pragma unroll
            for (int reg = 0; reg < 4; ++reg) {
                const int row = m0 + wr * 64 + i * 16 + quad * 4 + reg;
                C[(size_t)row * N + col] = acc[i][j][reg] + bv;
            }
        }
    }
}

// ---------------------------------------------------------------------------
// MFMA flash attention, v10 = v9 minus the NaN source:
//  * bf16 converts back to the PROVEN software f2bf (v_cvt_pk_bf16_f32 inline
//    asm produced zeros in the low half -> P==0 -> l==0 -> 0*inf = NaN).
//  * KEPT: exp2-domain softmax (SCALE2), EBuf rotation-16 bank de-conflict,
//    GEMM XCD swizzle. All math-verified.
// ---------------------------------------------------------------------------
#define QT 64
#define KT 64
#define NITEMS (B_ * H_ * (L_ / QT))   // 2048
#define PERSIST 768

__global__ __launch_bounds__(256, 3)
void attn_mfma(const ushort_t* __restrict__ q, const ushort_t* __restrict__ k,
               const ushort_t* __restrict__ v, const ushort_t* __restrict__ Erb,
               unsigned int* __restrict__ ctr, ushort_t* __restrict__ y)
{
    __shared__ __align__(16) ushort_t Kd[2][64 * 64];   // K tiles, swizzled
    __shared__ __align__(16) ushort_t Vt[2][64 * 64];   // [hs][key], swizzled
    __shared__ __align__(16) ushort_t EBuf[64][136];    // rolling QEr + P alias
    __shared__ int s_item;

    const int tid  = threadIdx.x;
    const int w    = tid >> 6;
    const int lane = tid & 63;
    const int quad = lane >> 4;
    const int lcol = lane & 15;
    const int rw   = w * 16 + quad * 4;

    // K async-staging constants (GEMM staging path)
    const int s_row = tid >> 3;                    // 0..31
    const int cgc   = (tid & 7) ^ (s_row & 7);     // swizzled source chunk
    // V transpose-staging constants: thread -> (key pair, hs block)
    const int vkp = (tid & 31) * 2;                // key pair base (even)
    const int vhb = (tid >> 5) * 8;                // hs block
    const int vkc = vkp >> 3, vks = vkp & 7;
    // fragment chunk offsets for Kd reads
    const int fs0 = ((quad) ^ (lcol & 7)) * 8;
    const int fs1 = ((4 + quad) ^ (lcol & 7)) * 8;

    // e-space rotation (bank de-conflict): rows quad>=2 rotate half by 16 cols
    const int rot = (quad & 2) << 3;               // 0 or 16
    const int sl0 = rot;                            // logical col 0  slot
    const int sl1 = (16 + rot) & 63;                // logical col 16 slot
    const int sl2 = (32 + rot) & 63;                // logical col 32 slot
    const int sl3 = (48 + rot) & 63;                // logical col 48 slot

    const short8 ones8 = {(short)0x3F80, (short)0x3F80, (short)0x3F80, (short)0x3F80,
                          (short)0x3F80, (short)0x3F80, (short)0x3F80, (short)0x3F80};

    for (;;) {
        if (tid == 0) s_item = (int)atomicAdd(ctr, 1u);
        __syncthreads();                 // broadcast item; also fences LDS reuse
        const int idx = s_item;
        if (idx >= NITEMS) break;

        // decode: windows of 8 bh x 32 qt, heavy-first within window
        const int wnd = idx >> 8;                 // 0..7
        const int sub = idx & 255;
        const int qt  = 31 - (sub >> 3);
        const int bh  = wnd * 8 + (sub & 7);
        const int qi0 = qt * QT;
        const int bb  = bh >> 4;
        const int hh  = bh & 15;
        const int cband = L_ - QT - qi0;

        const ushort_t* qp = q + (size_t)bh * L_ * HS_;
        const ushort_t* kp = k + (size_t)bh * L_ * HS_;
        const ushort_t* vp = v + (size_t)bh * L_ * HS_;

        // Q fragments (one-time per item, direct from global)
        const ushort_t* qrow = qp + (size_t)(qi0 + w * 16 + lcol) * HS_;
        const short8 aq0 = *(const short8*)(qrow + quad * 8);
        const short8 aq1 = *(const short8*)(qrow + 32 + quad * 8);

        // ---- prologue ----
        // EBuf chunk 0 via direct-global Er MFMAs (one-time, rotated slots)
        {
            const ushort_t* eb = Erb + (size_t)cband * HS_;
            f32x4 e0 = {0,0,0,0}, e1 = {0,0,0,0}, e2 = {0,0,0,0}, e3 = {0,0,0,0};
            e0 = MFMA(aq0, *(const short8*)(eb + (size_t)( 0 + lcol) * HS_ +      quad * 8), e0, 0,0,0);
            e1 = MFMA(aq0, *(const short8*)(eb + (size_t)(16 + lcol) * HS_ +      quad * 8), e1, 0,0,0);
            e2 = MFMA(aq0, *(const short8*)(eb + (size_t)(32 + lcol) * HS_ +      quad * 8), e2, 0,0,0);
            e3 = MFMA(aq0, *(const short8*)(eb + (size_t)(48 + lcol) * HS_ +      quad * 8), e3, 0,0,0);
            e0 = MFMA(aq1, *(const short8*)(eb + (size_t)( 0 + lcol) * HS_ + 32 + quad * 8), e0, 0,0,0);
            e1 = MFMA(aq1, *(const short8*)(eb + (size_t)(16 + lcol) * HS_ + 32 + quad * 8), e1, 0,0,0);
            e2 = MFMA(aq1, *(const short8*)(eb + (size_t)(32 + lcol) * HS_ + 32 + quad * 8), e2, 0,0,0);
            e3 = MFMA(aq1, *(const short8*)(eb + (size_t)(48 + lcol) * HS_ + 32 + quad * 8), e3, 0,0,0);
#pragma unroll
            for (int reg = 0; reg < 4; ++reg) {
                EBuf[rw + reg][sl0 + lcol] = f2bf(e0[reg]);
                EBuf[rw + reg][sl1 + lcol] = f2bf(e1[reg]);
                EBuf[rw + reg][sl2 + lcol] = f2bf(e2[reg]);
                EBuf[rw + reg][sl3 + lcol] = f2bf(e3[reg]);
            }
        }
        // stage K tile 0 -> Kd[0]
        {
            const ushort_t* g = kp + (size_t)s_row * HS_ + cgc * 8;
            gload_lds16(g,            &Kd[0][tid * 8]);
            gload_lds16(g + 32 * HS_, &Kd[0][2048 + tid * 8]);
        }
        // Er fragments for chunk 1 -> regs (row-clamped)
        short8 erf[8];
#pragma unroll
        for (int nt = 0; nt < 4; ++nt) {
            int r = cband + 64 + nt * 16 + lcol;
            if (r > L_ - 1) r = L_ - 1;
            const ushort_t* p = Erb + (size_t)r * HS_ + quad * 8;
            erf[nt * 2]     = *(const short8*)p;
            erf[nt * 2 + 1] = *(const short8*)(p + 32);
        }
        // V tile 0 -> Vt[0] (sync reg round-trip, packed b32 swizzled write)
        {
            const ushort_t* src = vp + (size_t)vkp * HS_ + vhb;
            uint4 a = *(const uint4*)src;
            uint4 b = *(const uint4*)(src + HS_);
            const ushort_t* pa = (const ushort_t*)&a;
            const ushort_t* pb = (const ushort_t*)&b;
#pragma unroll
            for (int u = 0; u < 8; ++u) {
                const int hs = vhb + u;
                const int f = ((hs >> 3) & 7) ^ (hs & 7);
                const unsigned int val = (unsigned int)pa[u] | ((unsigned int)pb[u] << 16);
                *(unsigned int*)&Vt[0][hs * 64 + ((vkc ^ f) << 3) + vks] = val;
            }
        }
        // V tile 1 -> regs (unused if qt==0; rows always in-bounds)
        uint4 va, vb;
        {
            const ushort_t* src = vp + (size_t)(KT + vkp) * HS_ + vhb;
            va = *(const uint4*)src; vb = *(const uint4*)(src + HS_);
        }

        f32x4 O[4];
#pragma unroll
        for (int nt = 0; nt < 4; ++nt) O[nt] = (f32x4){0, 0, 0, 0};
        float m_r[4] = {-INFINITY, -INFINITY, -INFINITY, -INFINITY};
        float l_r[4] = {0, 0, 0, 0};

        for (int kt = 0; kt <= qt; ++kt) {
            const int kj0 = kt * KT;
            const int cur = kt & 1, nxt = cur ^ 1;

            __syncthreads();   // drains last iter's async stages; orders buffers

            if (kt < qt) {
                // write Vt[nxt] <- V tile kt+1 (regs loaded last iter)
                {
                    const ushort_t* pa = (const ushort_t*)&va;
                    const ushort_t* pb = (const ushort_t*)&vb;
#pragma unroll
                    for (int u = 0; u < 8; ++u) {
                        const int hs = vhb + u;
                        const int f = ((hs >> 3) & 7) ^ (hs & 7);
                        const unsigned int val = (unsigned int)pa[u] | ((unsigned int)pb[u] << 16);
                        *(unsigned int*)&Vt[nxt][hs * 64 + ((vkc ^ f) << 3) + vks] = val;
                    }
                }
                // issue V tile kt+2 -> regs (row-clamped)
                {
                    int kj2 = (kt + 2) * KT;
                    if (kj2 > L_ - KT) kj2 = L_ - KT;
                    const ushort_t* src = vp + (size_t)(kj2 + vkp) * HS_ + vhb;
                    va = *(const uint4*)src; vb = *(const uint4*)(src + HS_);
                }
                // issue K tile kt+1 -> Kd[nxt]
                {
                    const ushort_t* g = kp + (size_t)((kt + 1) * KT + s_row) * HS_ + cgc * 8;
                    gload_lds16(g,            &Kd[nxt][tid * 8]);
                    gload_lds16(g + 32 * HS_, &Kd[nxt][2048 + tid * 8]);
                }
            }

            // ---- QEr chunk kt+1 from erf regs ----
            f32x4 e0 = {0,0,0,0}, e1 = {0,0,0,0}, e2 = {0,0,0,0}, e3 = {0,0,0,0};
            e0 = MFMA(aq0, erf[0], e0, 0,0,0);
            e1 = MFMA(aq0, erf[2], e1, 0,0,0);
            e2 = MFMA(aq0, erf[4], e2, 0,0,0);
            e3 = MFMA(aq0, erf[6], e3, 0,0,0);
            e0 = MFMA(aq1, erf[1], e0, 0,0,0);
            e1 = MFMA(aq1, erf[3], e1, 0,0,0);
            e2 = MFMA(aq1, erf[5], e2, 0,0,0);
            e3 = MFMA(aq1, erf[7], e3, 0,0,0);

            // reload erf <- Er fragments for chunk kt+2 (WAR; lands next iter)
            {
                const int ebase = cband + (kt + 2) * 64;
#pragma unroll
                for (int nt = 0; nt < 4; ++nt) {
                    int r = ebase + nt * 16 + lcol;
                    if (r > L_ - 1) r = L_ - 1;
                    const ushort_t* p = Erb + (size_t)r * HS_ + quad * 8;
                    erf[nt * 2]     = *(const short8*)p;
                    erf[nt * 2 + 1] = *(const short8*)(p + 32);
                }
            }

            {
                const int par = nxt * 64;   // chunk kt+1 (rotated slots)
#pragma unroll
                for (int reg = 0; reg < 4; ++reg) {
                    ushort_t* pr = &EBuf[rw + reg][par];
                    pr[sl0 + lcol] = f2bf(e0[reg]);
                    pr[sl1 + lcol] = f2bf(e1[reg]);
                    pr[sl2 + lcol] = f2bf(e2[reg]);
                    pr[sl3 + lcol] = f2bf(e3[reg]);
                }
            }

            // ---- scores from Kd[cur] ----
            f32x4 s0 = {0,0,0,0}, s1 = {0,0,0,0}, s2 = {0,0,0,0}, s3 = {0,0,0,0};
            s0 = MFMA(aq0, *(const short8*)&Kd[cur][( 0 + lcol) * 64 + fs0], s0, 0,0,0);
            s1 = MFMA(aq0, *(const short8*)&Kd[cur][(16 + lcol) * 64 + fs0], s1, 0,0,0);
            s2 = MFMA(aq0, *(const short8*)&Kd[cur][(32 + lcol) * 64 + fs0], s2, 0,0,0);
            s3 = MFMA(aq0, *(const short8*)&Kd[cur][(48 + lcol) * 64 + fs0], s3, 0,0,0);
            s0 = MFMA(aq1, *(const short8*)&Kd[cur][( 0 + lcol) * 64 + fs1], s0, 0,0,0);
            s1 = MFMA(aq1, *(const short8*)&Kd[cur][(16 + lcol) * 64 + fs1], s1, 0,0,0);
            s2 = MFMA(aq1, *(const short8*)&Kd[cur][(32 + lcol) * 64 + fs1], s2, 0,0,0);
            s3 = MFMA(aq1, *(const short8*)&Kd[cur][(48 + lcol) * 64 + fs1], s3, 0,0,0);

            float p_[4][4];
            float al[4];
            const float sq[4][4] = {
                {s0[0], s0[1], s0[2], s0[3]},
                {s1[0], s1[1], s1[2], s1[3]},
                {s2[0], s2[1], s2[2], s2[3]},
                {s3[0], s3[1], s3[2], s3[3]}};
            const bool diag = (kt == qt);
#pragma unroll
            for (int reg = 0; reg < 4; ++reg) {
                const int r = rw + reg;                       // within-tile row
                const ushort_t* erow = EBuf[r];
                const int cb0 = (63 - r + kj0 + lcol) & 127;  // logical col base
                float scr[4];
#pragma unroll
                for (int nt = 0; nt < 4; ++nt) {
                    int c = cb0 + nt * 16; c &= 127;           // logical col
                    const int col = (c & 64) | ((c + rot) & 63); // rotated phys
                    float sv = (sq[nt][reg] + bf2f(erow[col])) * SCALE2;
                    if (diag && nt * 16 + lcol > r) sv = -INFINITY;
                    scr[nt] = sv;
                }
                float mx = fmaxf(fmaxf(scr[0], scr[1]), fmaxf(scr[2], scr[3]));
                mx = fmaxf(mx, __shfl_xor(mx, 1));
                mx = fmaxf(mx, __shfl_xor(mx, 2));
                mx = fmaxf(mx, __shfl_xor(mx, 4));
                mx = fmaxf(mx, __shfl_xor(mx, 8));
                const float nm = fmaxf(m_r[reg], mx);
                const float a_ = exp2f(m_r[reg] - nm);
                m_r[reg] = nm;
#pragma unroll
                for (int nt = 0; nt < 4; ++nt)
                    p_[nt][reg] = exp2f(scr[nt] - nm);
                al[reg] = a_;
            }
#pragma unroll
            for (int nt = 0; nt < 4; ++nt)
#pragma unroll
                for (int reg = 0; reg < 4; ++reg) O[nt][reg] *= al[reg];

            // P: wave-private round-trip through EBuf's dead chunk-half
            // (plain addressing; complete overwrite of the half)
            {
#pragma unroll
                for (int reg = 0; reg < 4; ++reg) {
                    ushort_t* pr = &EBuf[rw + reg][cur * 64];
                    pr[ 0 + lcol] = f2bf(p_[0][reg]);
                    pr[16 + lcol] = f2bf(p_[1][reg]);
                    pr[32 + lcol] = f2bf(p_[2][reg]);
                    pr[48 + lcol] = f2bf(p_[3][reg]);
                }
            }
            const short8 ap0 = *(const short8*)&EBuf[w * 16 + lcol][cur * 64 + quad * 8];
            const short8 ap1 = *(const short8*)&EBuf[w * 16 + lcol][cur * 64 + 32 + quad * 8];

            // row-sum of P via ones-MFMA (replaces the shfl sum tree)
            f32x4 lacc = {0, 0, 0, 0};
            lacc = MFMA(ap0, ones8, lacc, 0, 0, 0);
            lacc = MFMA(ap1, ones8, lacc, 0, 0, 0);
#pragma unroll
            for (int reg = 0; reg < 4; ++reg)
                l_r[reg] = l_r[reg] * al[reg] + lacc[reg];

            // PV: swizzled Vt[cur] fragment reads
            {
#pragma unroll
                for (int nt = 0; nt < 4; ++nt) {
                    const int hs = nt * 16 + lcol;
                    const int f = ((hs >> 3) & 7) ^ (hs & 7);
                    const short8 bv0 = *(const short8*)&Vt[cur][hs * 64 + ((quad ^ f) << 3)];
                    const short8 bv1 = *(const short8*)&Vt[cur][hs * 64 + (((4 + quad) ^ f) << 3)];
                    O[nt] = MFMA(ap0, bv0, O[nt], 0, 0, 0);
                    O[nt] = MFMA(ap1, bv1, O[nt], 0, 0, 0);
                }
            }
        }

        float inv[4];
#pragma unroll
        for (int reg = 0; reg < 4; ++reg) inv[reg] = 1.f / l_r[reg];
#pragma unroll
        for (int nt = 0; nt < 4; ++nt) {
#pragma unroll
            for (int reg = 0; reg < 4; ++reg) {
                const int r = w * 16 + quad * 4 + reg;
                y[(((size_t)bb * L_ + qi0 + r) * H_ + hh) * HS_ + nt * 16 + lcol] =
                    f2bf(O[nt][reg] * inv[reg]);
            }
        }
    }
}

// ---------------------------------------------------------------------------
extern "C" void kernel_launch(void* const* d_in, const int* in_sizes, int n_in,
                              void* d_out, int out_size, void* d_ws, size_t ws_size,
                              hipStream_t stream)
{
    const float* x      = (const float*)d_in[0];   // [B,L,D]
    const float* W_attn = (const float*)d_in[1];   // [D,3D]
    const float* b_attn = (const float*)d_in[2];   // [3D]
    const float* W_proj = (const float*)d_in[3];   // [D,D]
    const float* b_proj = (const float*)d_in[4];   // [D]
    const float* Er     = (const float*)d_in[5];   // [L,HS] fp32
    float* out = (float*)d_out;

    const size_t per = (size_t)B_ * H_ * L_ * HS_;   // 8388608
    ushort_t* qb  = (ushort_t*)d_ws;                 // bf16 q|k|v
    ushort_t* kb  = qb + per;
    ushort_t* vb  = kb + per;
    ushort_t* yb  = vb + per;                        // bf16 [B][L][D]
    ushort_t* xb  = yb + per;                        // bf16 x
    ushort_t* wat = xb + per;                        // W_attn^T bf16 [3072][1024]
    ushort_t* wpt = wat + (size_t)3 * D_ * D_;       // W_proj^T bf16 [1024][1024]
    ushort_t* erb = wpt + (size_t)D_ * D_;           // Er bf16 [L][HS]
    unsigned int* ctr = (unsigned int*)(erb + (size_t)L_ * HS_);  // work counter

    dim3 blk(256);

    conv_to_bf16<<<dim3((B_ * L_ * D_) / 2048), blk, 0, stream>>>(x, xb);
    conv_to_bf16<<<dim3((L_ * HS_) / 2048), blk, 0, stream>>>(Er, erb);
    zero_u32<<<dim3(1), dim3(1), 0, stream>>>(ctr);
    transpose_to_bf16<<<dim3(3 * D_ / 64, D_ / 64), blk, 0, stream>>>(W_attn, wat, D_, 3 * D_);
    transpose_to_bf16<<<dim3(D_ / 64, D_ / 64), blk, 0, stream>>>(W_proj, wpt, D_, D_);

    qkv_mfma<<<dim3(3 * D_ / 128, B_ * L_ / 128), blk, 0, stream>>>(xb, wat, b_attn, qb);

    attn_mfma<<<dim3(PERSIST), blk, 0, stream>>>(qb, kb, vb, erb, ctr, yb);

    proj_mfma<<<dim3(D_ / 128, B_ * L_ / 128), blk, 0, stream>>>(yb, wpt, b_proj, out);
}

// Round 10
// 422.412 us; speedup vs baseline: 1.0754x; 1.0754x over previous
//
#include <hip/hip_runtime.h>
#include <hip/hip_bf16.h>
#include <math.h>

#define B_  4
#define L_  2048
#define D_  1024
#define H_  16
#define HS_ 64
#define SCALE 0.125f   // 1/sqrt(64)

typedef unsigned short ushort_t;
typedef __attribute__((ext_vector_type(8))) short short8;
typedef __attribute__((ext_vector_type(4))) float f32x4;

#define MFMA __builtin_amdgcn_mfma_f32_16x16x32_bf16

static __device__ __forceinline__ ushort_t f2bf(float f) {
    union { float f; unsigned int u; } cv; cv.f = f;
    unsigned int u = cv.u;
    unsigned int r = (u + 0x7FFFu + ((u >> 16) & 1u)) >> 16;   // RNE
    return (ushort_t)r;
}
static __device__ __forceinline__ float bf2f(ushort_t h) {
    union { float f; unsigned int u; } cv; cv.u = ((unsigned int)h) << 16;
    return cv.f;
}

static __device__ __forceinline__ void gload_lds16(const ushort_t* g, ushort_t* l) {
    __builtin_amdgcn_global_load_lds(
        (const __attribute__((address_space(1))) unsigned int*)g,
        (__attribute__((address_space(3))) unsigned int*)l, 16, 0, 0);
}

// ---------------------------------------------------------------------------
// Prep kernels: fp32 -> bf16 (x, Er), fp32 -> bf16 transposed (weights)
// ---------------------------------------------------------------------------
__global__ __launch_bounds__(256)
void conv_to_bf16(const float* __restrict__ x, ushort_t* __restrict__ xb)
{
    const size_t i = (size_t)blockIdx.x * 256 + threadIdx.x;   // 8 elems/thread
    const float4* src = (const float4*)x + i * 2;
    float4 a = src[0], b = src[1];
    ushort_t o[8] = {f2bf(a.x), f2bf(a.y), f2bf(a.z), f2bf(a.w),
                     f2bf(b.x), f2bf(b.y), f2bf(b.z), f2bf(b.w)};
    *(uint4*)(xb + i * 8) = *(uint4*)o;
}

__global__ void zero_u32(unsigned int* __restrict__ p) { *p = 0u; }

__global__ __launch_bounds__(256)
void transpose_to_bf16(const float* __restrict__ W, ushort_t* __restrict__ Wt,
                       int K, int N)   // W:[K][N] -> Wt:[N][K]
{
    __shared__ ushort_t tile[64][65];
    const int tid = threadIdx.x;
    const int n0 = blockIdx.x * 64, k0 = blockIdx.y * 64;
#pragma unroll
    for (int s = 0; s < 16; ++s) {
        const int idx = s * 256 + tid;
        const int kl = idx >> 6, nl = idx & 63;
        tile[nl][kl] = f2bf(W[(size_t)(k0 + kl) * N + n0 + nl]);
    }
    __syncthreads();
#pragma unroll
    for (int s = 0; s < 8; ++s) {
        const int idx = s * 256 + tid;
        const int nl = idx >> 5, kc = idx & 31;
        const unsigned int vlo = tile[nl][kc * 2];
        const unsigned int vhi = tile[nl][kc * 2 + 1];
        *(unsigned int*)(Wt + (size_t)(n0 + nl) * K + k0 + kc * 2) =
            vlo | (vhi << 16);
    }
}

// ---------------------------------------------------------------------------
// m97-style bf16 MFMA GEMM: C[M][N] = A[M][K] @ Bt[N][K]^T
// + XCD-bijective block swizzle (grids 1536/512, both %8==0) — validated R9:
//   non-attn time 159.8 -> 154.0 us.
// ---------------------------------------------------------------------------
__global__ __launch_bounds__(256)
void qkv_mfma(const ushort_t* __restrict__ A, const ushort_t* __restrict__ Bt,
              const float* __restrict__ bias, ushort_t* __restrict__ qkv)
{
    __shared__ __align__(16) ushort_t As[128 * 64];
    __shared__ __align__(16) ushort_t Bs[128 * 64];

    const int tid = threadIdx.x;
    const int w = tid >> 6, lane = tid & 63, quad = lane >> 4, lcol = lane & 15;
    const int wr = w >> 1, wc = w & 1;
    unsigned wg = blockIdx.y * gridDim.x + blockIdx.x;
    const unsigned nwg = gridDim.x * gridDim.y;
    wg = (wg & 7) * (nwg >> 3) + (wg >> 3);
    const int m0 = (int)(wg / gridDim.x) * 128;
    const int n0 = (int)(wg % gridDim.x) * 128;
    const int K = D_;

    const int srow = tid >> 3;
    const int cg = (tid & 7) ^ (srow & 7);
    const ushort_t* gA = A + (size_t)(m0 + srow) * K + cg * 8;
    const ushort_t* gB = Bt + (size_t)(n0 + srow) * K + cg * 8;
    ushort_t* lA = As + tid * 8;
    ushort_t* lB = Bs + tid * 8;

    const int cs0 = ((quad) ^ (lcol & 7)) * 8;
    const int cs1 = ((4 + quad) ^ (lcol & 7)) * 8;

    f32x4 acc[4][4];
#pragma unroll
    for (int i = 0; i < 4; ++i)
#pragma unroll
        for (int j = 0; j < 4; ++j) acc[i][j] = (f32x4){0, 0, 0, 0};

    for (int k0 = 0; k0 < K; k0 += 64) {
        __syncthreads();
#pragma unroll
        for (int s = 0; s < 4; ++s) {
            gload_lds16(gA + k0 + (size_t)s * 32 * K, lA + s * 2048);
            gload_lds16(gB + k0 + (size_t)s * 32 * K, lB + s * 2048);
        }
        __syncthreads();
#pragma unroll
        for (int kk = 0; kk < 2; ++kk) {
            const int cs = kk ? cs1 : cs0;
            short8 af[4], bf[4];
#pragma unroll
            for (int i = 0; i < 4; ++i)
                af[i] = *(const short8*)&As[(wr * 64 + i * 16 + lcol) * 64 + cs];
#pragma unroll
            for (int j = 0; j < 4; ++j)
                bf[j] = *(const short8*)&Bs[(wc * 64 + j * 16 + lcol) * 64 + cs];
#pragma unroll
            for (int i = 0; i < 4; ++i)
#pragma unroll
                for (int j = 0; j < 4; ++j)
                    acc[i][j] = MFMA(af[i], bf[j], acc[i][j], 0, 0, 0);
        }
    }

    const size_t per = (size_t)B_ * H_ * L_ * HS_;
#pragma unroll
    for (int j = 0; j < 4; ++j) {
        const int col = n0 + wc * 64 + j * 16 + lcol;
        const float bv = bias[col];
        const int sel = col >> 10;
        const int within = col & 1023;
        const int hh = within >> 6, hs = within & 63;
        ushort_t* base = qkv + (size_t)sel * per;
#pragma unroll
        for (int i = 0; i < 4; ++i) {
#pragma unroll
            for (int reg = 0; reg < 4; ++reg) {
                const int row = m0 + wr * 64 + i * 16 + quad * 4 + reg;
                const int bb = row >> 11, ll = row & 2047;
                base[(((size_t)(bb * H_ + hh)) * L_ + ll) * HS_ + hs] =
                    f2bf(acc[i][j][reg] + bv);
            }
        }
    }
}

__global__ __launch_bounds__(256)
void proj_mfma(const ushort_t* __restrict__ A, const ushort_t* __restrict__ Bt,
               const float* __restrict__ bias, float* __restrict__ C)
{
    __shared__ __align__(16) ushort_t As[128 * 64];
    __shared__ __align__(16) ushort_t Bs[128 * 64];

    const int tid = threadIdx.x;
    const int w = tid >> 6, lane = tid & 63, quad = lane >> 4, lcol = lane & 15;
    const int wr = w >> 1, wc = w & 1;
    unsigned wg = blockIdx.y * gridDim.x + blockIdx.x;
    const unsigned nwg = gridDim.x * gridDim.y;
    wg = (wg & 7) * (nwg >> 3) + (wg >> 3);
    const int m0 = (int)(wg / gridDim.x) * 128;
    const int n0 = (int)(wg % gridDim.x) * 128;
    const int K = D_;
    const int N = D_;

    const int srow = tid >> 3;
    const int cg = (tid & 7) ^ (srow & 7);
    const ushort_t* gA = A + (size_t)(m0 + srow) * K + cg * 8;
    const ushort_t* gB = Bt + (size_t)(n0 + srow) * K + cg * 8;
    ushort_t* lA = As + tid * 8;
    ushort_t* lB = Bs + tid * 8;

    const int cs0 = ((quad) ^ (lcol & 7)) * 8;
    const int cs1 = ((4 + quad) ^ (lcol & 7)) * 8;

    f32x4 acc[4][4];
#pragma unroll
    for (int i = 0; i < 4; ++i)
#pragma unroll
        for (int j = 0; j < 4; ++j) acc[i][j] = (f32x4){0, 0, 0, 0};

    for (int k0 = 0; k0 < K; k0 += 64) {
        __syncthreads();
#pragma unroll
        for (int s = 0; s < 4; ++s) {
            gload_lds16(gA + k0 + (size_t)s * 32 * K, lA + s * 2048);
            gload_lds16(gB + k0 + (size_t)s * 32 * K, lB + s * 2048);
        }
        __syncthreads();
#pragma unroll
        for (int kk = 0; kk < 2; ++kk) {
            const int cs = kk ? cs1 : cs0;
            short8 af[4], bf[4];
#pragma unroll
            for (int i = 0; i < 4; ++i)
                af[i] = *(const short8*)&As[(wr * 64 + i * 16 + lcol) * 64 + cs];
#pragma unroll
            for (int j = 0; j < 4; ++j)
                bf[j] = *(const short8*)&Bs[(wc * 64 + j * 16 + lcol) * 64 + cs];
#pragma unroll
            for (int i = 0; i < 4; ++i)
#pragma unroll
                for (int j = 0; j < 4; ++j)
                    acc[i][j] = MFMA(af[i], bf[j], acc[i][j], 0, 0, 0);
        }
    }

#pragma unroll
    for (int j = 0; j < 4; ++j) {
        const int col = n0 + wc * 64 + j * 16 + lcol;
        const float bv = bias[col];
#pragma unroll
        for (int i = 0; i < 4; ++i) {
#pragma unroll
            for (int reg = 0; reg < 4; ++reg) {
                const int row = m0 + wr * 64 + i * 16 + quad * 4 + reg;
                C[(size_t)row * N + col] = acc[i][j][reg] + bv;
            }
        }
    }
}

// ---------------------------------------------------------------------------
// MFMA flash attention, v11 = EXACT R7 kernel (best measured: 265 us).
// R8/R9 deltas reverted with counter evidence:
//  * EBuf rotation: conflicts unchanged (5406720 invariant R3-R9) — the
//    160 cyc/block-iter is NOT from band reads; rotation only added VALU.
//  * exp2f: libm exp2 is MORE VALU than __expf's mul+v_exp (46% vs 40% busy).
//  * v_cvt_pk inline asm: NaN (R8).
// Kept from the validated ledger: persistent work-stealing (R4), Kd via
// global_load_lds + erf reg prefetch (R4), ones-MFMA row-sum (R7),
// launch_bounds(256,3) (R6: K-in-regs/4-block variants spill).
// ---------------------------------------------------------------------------
#define QT 64
#define KT 64
#define NITEMS (B_ * H_ * (L_ / QT))   // 2048
#define PERSIST 768

__global__ __launch_bounds__(256, 3)
void attn_mfma(const ushort_t* __restrict__ q, const ushort_t* __restrict__ k,
               const ushort_t* __restrict__ v, const ushort_t* __restrict__ Erb,
               unsigned int* __restrict__ ctr, ushort_t* __restrict__ y)
{
    __shared__ __align__(16) ushort_t Kd[2][64 * 64];   // K tiles, swizzled
    __shared__ __align__(16) ushort_t Vt[2][64 * 64];   // [hs][key], swizzled
    __shared__ __align__(16) ushort_t EBuf[64][136];    // rolling QEr + P alias
    __shared__ int s_item;

    const int tid  = threadIdx.x;
    const int w    = tid >> 6;
    const int lane = tid & 63;
    const int quad = lane >> 4;
    const int lcol = lane & 15;
    const int rw   = w * 16 + quad * 4;

    // K async-staging constants (GEMM staging path)
    const int s_row = tid >> 3;                    // 0..31
    const int cgc   = (tid & 7) ^ (s_row & 7);     // swizzled source chunk
    // V transpose-staging constants: thread -> (key pair, hs block)
    const int vkp = (tid & 31) * 2;                // key pair base (even)
    const int vhb = (tid >> 5) * 8;                // hs block
    const int vkc = vkp >> 3, vks = vkp & 7;
    // fragment chunk offsets for Kd reads
    const int fs0 = ((quad) ^ (lcol & 7)) * 8;
    const int fs1 = ((4 + quad) ^ (lcol & 7)) * 8;

    const short8 ones8 = {(short)0x3F80, (short)0x3F80, (short)0x3F80, (short)0x3F80,
                          (short)0x3F80, (short)0x3F80, (short)0x3F80, (short)0x3F80};

    for (;;) {
        if (tid == 0) s_item = (int)atomicAdd(ctr, 1u);
        __syncthreads();                 // broadcast item; also fences LDS reuse
        const int idx = s_item;
        if (idx >= NITEMS) break;

        // decode: windows of 8 bh x 32 qt, heavy-first within window
        const int wnd = idx >> 8;                 // 0..7
        const int sub = idx & 255;
        const int qt  = 31 - (sub >> 3);
        const int bh  = wnd * 8 + (sub & 7);
        const int qi0 = qt * QT;
        const int bb  = bh >> 4;
        const int hh  = bh & 15;
        const int cband = L_ - QT - qi0;

        const ushort_t* qp = q + (size_t)bh * L_ * HS_;
        const ushort_t* kp = k + (size_t)bh * L_ * HS_;
        const ushort_t* vp = v + (size_t)bh * L_ * HS_;

        // Q fragments (one-time per item, direct from global)
        const ushort_t* qrow = qp + (size_t)(qi0 + w * 16 + lcol) * HS_;
        const short8 aq0 = *(const short8*)(qrow + quad * 8);
        const short8 aq1 = *(const short8*)(qrow + 32 + quad * 8);

        // ---- prologue ----
        // EBuf chunk 0 via direct-global Er MFMAs (one-time)
        {
            const ushort_t* eb = Erb + (size_t)cband * HS_;
            f32x4 e0 = {0,0,0,0}, e1 = {0,0,0,0}, e2 = {0,0,0,0}, e3 = {0,0,0,0};
            e0 = MFMA(aq0, *(const short8*)(eb + (size_t)( 0 + lcol) * HS_ +      quad * 8), e0, 0,0,0);
            e1 = MFMA(aq0, *(const short8*)(eb + (size_t)(16 + lcol) * HS_ +      quad * 8), e1, 0,0,0);
            e2 = MFMA(aq0, *(const short8*)(eb + (size_t)(32 + lcol) * HS_ +      quad * 8), e2, 0,0,0);
            e3 = MFMA(aq0, *(const short8*)(eb + (size_t)(48 + lcol) * HS_ +      quad * 8), e3, 0,0,0);
            e0 = MFMA(aq1, *(const short8*)(eb + (size_t)( 0 + lcol) * HS_ + 32 + quad * 8), e0, 0,0,0);
            e1 = MFMA(aq1, *(const short8*)(eb + (size_t)(16 + lcol) * HS_ + 32 + quad * 8), e1, 0,0,0);
            e2 = MFMA(aq1, *(const short8*)(eb + (size_t)(32 + lcol) * HS_ + 32 + quad * 8), e2, 0,0,0);
            e3 = MFMA(aq1, *(const short8*)(eb + (size_t)(48 + lcol) * HS_ + 32 + quad * 8), e3, 0,0,0);
#pragma unroll
            for (int reg = 0; reg < 4; ++reg) {
                EBuf[rw + reg][ 0 + lcol] = f2bf(e0[reg]);
                EBuf[rw + reg][16 + lcol] = f2bf(e1[reg]);
                EBuf[rw + reg][32 + lcol] = f2bf(e2[reg]);
                EBuf[rw + reg][48 + lcol] = f2bf(e3[reg]);
            }
        }
        // stage K tile 0 -> Kd[0]
        {
            const ushort_t* g = kp + (size_t)s_row * HS_ + cgc * 8;
            gload_lds16(g,            &Kd[0][tid * 8]);
            gload_lds16(g + 32 * HS_, &Kd[0][2048 + tid * 8]);
        }
        // Er fragments for chunk 1 -> regs (row-clamped)
        short8 erf[8];
#pragma unroll
        for (int nt = 0; nt < 4; ++nt) {
            int r = cband + 64 + nt * 16 + lcol;
            if (r > L_ - 1) r = L_ - 1;
            const ushort_t* p = Erb + (size_t)r * HS_ + quad * 8;
            erf[nt * 2]     = *(const short8*)p;
            erf[nt * 2 + 1] = *(const short8*)(p + 32);
        }
        // V tile 0 -> Vt[0] (sync reg round-trip, packed b32 swizzled write)
        {
            const ushort_t* src = vp + (size_t)vkp * HS_ + vhb;
            uint4 a = *(const uint4*)src;
            uint4 b = *(const uint4*)(src + HS_);
            const ushort_t* pa = (const ushort_t*)&a;
            const ushort_t* pb = (const ushort_t*)&b;
#pragma unroll
            for (int u = 0; u < 8; ++u) {
                const int hs = vhb + u;
                const int f = ((hs >> 3) & 7) ^ (hs & 7);
                const unsigned int val = (unsigned int)pa[u] | ((unsigned int)pb[u] << 16);
                *(unsigned int*)&Vt[0][hs * 64 + ((vkc ^ f) << 3) + vks] = val;
            }
        }
        // V tile 1 -> regs (unused if qt==0; rows always in-bounds)
        uint4 va, vb;
        {
            const ushort_t* src = vp + (size_t)(KT + vkp) * HS_ + vhb;
            va = *(const uint4*)src; vb = *(const uint4*)(src + HS_);
        }

        f32x4 O[4];
#pragma unroll
        for (int nt = 0; nt < 4; ++nt) O[nt] = (f32x4){0, 0, 0, 0};
        float m_r[4] = {-INFINITY, -INFINITY, -INFINITY, -INFINITY};
        float l_r[4] = {0, 0, 0, 0};

        for (int kt = 0; kt <= qt; ++kt) {
            const int kj0 = kt * KT;
            const int cur = kt & 1, nxt = cur ^ 1;

            __syncthreads();   // drains last iter's async stages; orders buffers

            if (kt < qt) {
                // write Vt[nxt] <- V tile kt+1 (regs loaded last iter)
                {
                    const ushort_t* pa = (const ushort_t*)&va;
                    const ushort_t* pb = (const ushort_t*)&vb;
#pragma unroll
                    for (int u = 0; u < 8; ++u) {
                        const int hs = vhb + u;
                        const int f = ((hs >> 3) & 7) ^ (hs & 7);
                        const unsigned int val = (unsigned int)pa[u] | ((unsigned int)pb[u] << 16);
                        *(unsigned int*)&Vt[nxt][hs * 64 + ((vkc ^ f) << 3) + vks] = val;
                    }
                }
                // issue V tile kt+2 -> regs (row-clamped)
                {
                    int kj2 = (kt + 2) * KT;
                    if (kj2 > L_ - KT) kj2 = L_ - KT;
                    const ushort_t* src = vp + (size_t)(kj2 + vkp) * HS_ + vhb;
                    va = *(const uint4*)src; vb = *(const uint4*)(src + HS_);
                }
                // issue K tile kt+1 -> Kd[nxt]
                {
                    const ushort_t* g = kp + (size_t)((kt + 1) * KT + s_row) * HS_ + cgc * 8;
                    gload_lds16(g,            &Kd[nxt][tid * 8]);
                    gload_lds16(g + 32 * HS_, &Kd[nxt][2048 + tid * 8]);
                }
            }

            // ---- QEr chunk kt+1 from erf regs ----
            f32x4 e0 = {0,0,0,0}, e1 = {0,0,0,0}, e2 = {0,0,0,0}, e3 = {0,0,0,0};
            e0 = MFMA(aq0, erf[0], e0, 0,0,0);
            e1 = MFMA(aq0, erf[2], e1, 0,0,0);
            e2 = MFMA(aq0, erf[4], e2, 0,0,0);
            e3 = MFMA(aq0, erf[6], e3, 0,0,0);
            e0 = MFMA(aq1, erf[1], e0, 0,0,0);
            e1 = MFMA(aq1, erf[3], e1, 0,0,0);
            e2 = MFMA(aq1, erf[5], e2, 0,0,0);
            e3 = MFMA(aq1, erf[7], e3, 0,0,0);

            // reload erf <- Er fragments for chunk kt+2 (WAR; lands next iter)
            {
                const int ebase = cband + (kt + 2) * 64;
#pragma unroll
                for (int nt = 0; nt < 4; ++nt) {
                    int r = ebase + nt * 16 + lcol;
                    if (r > L_ - 1) r = L_ - 1;
                    const ushort_t* p = Erb + (size_t)r * HS_ + quad * 8;
                    erf[nt * 2]     = *(const short8*)p;
                    erf[nt * 2 + 1] = *(const short8*)(p + 32);
                }
            }

            {
                const int par = nxt * 64;   // chunk kt+1
#pragma unroll
                for (int reg = 0; reg < 4; ++reg) {
                    EBuf[rw + reg][par +  0 + lcol] = f2bf(e0[reg]);
                    EBuf[rw + reg][par + 16 + lcol] = f2bf(e1[reg]);
                    EBuf[rw + reg][par + 32 + lcol] = f2bf(e2[reg]);
                    EBuf[rw + reg][par + 48 + lcol] = f2bf(e3[reg]);
                }
            }

            // ---- scores from Kd[cur] ----
            f32x4 s0 = {0,0,0,0}, s1 = {0,0,0,0}, s2 = {0,0,0,0}, s3 = {0,0,0,0};
            s0 = MFMA(aq0, *(const short8*)&Kd[cur][( 0 + lcol) * 64 + fs0], s0, 0,0,0);
            s1 = MFMA(aq0, *(const short8*)&Kd[cur][(16 + lcol) * 64 + fs0], s1, 0,0,0);
            s2 = MFMA(aq0, *(const short8*)&Kd[cur][(32 + lcol) * 64 + fs0], s2, 0,0,0);
            s3 = MFMA(aq0, *(const short8*)&Kd[cur][(48 + lcol) * 64 + fs0], s3, 0,0,0);
            s0 = MFMA(aq1, *(const short8*)&Kd[cur][( 0 + lcol) * 64 + fs1], s0, 0,0,0);
            s1 = MFMA(aq1, *(const short8*)&Kd[cur][(16 + lcol) * 64 + fs1], s1, 0,0,0);
            s2 = MFMA(aq1, *(const short8*)&Kd[cur][(32 + lcol) * 64 + fs1], s2, 0,0,0);
            s3 = MFMA(aq1, *(const short8*)&Kd[cur][(48 + lcol) * 64 + fs1], s3, 0,0,0);

            float p_[4][4];
            float al[4];
            const float sq[4][4] = {
                {s0[0], s0[1], s0[2], s0[3]},
                {s1[0], s1[1], s1[2], s1[3]},
                {s2[0], s2[1], s2[2], s2[3]},
                {s3[0], s3[1], s3[2], s3[3]}};
#pragma unroll
            for (int reg = 0; reg < 4; ++reg) {
                const int r = w * 16 + quad * 4 + reg;
                float scr[4];
#pragma unroll
                for (int nt = 0; nt < 4; ++nt) {
                    const int jl = nt * 16 + lcol;
                    const int c = (63 - r + jl + kj0) & 127;
                    float sv = (sq[nt][reg] + bf2f(EBuf[r][c])) * SCALE;
                    if (kt == qt && jl > r) sv = -INFINITY;
                    scr[nt] = sv;
                }
                float mx = fmaxf(fmaxf(scr[0], scr[1]), fmaxf(scr[2], scr[3]));
                mx = fmaxf(mx, __shfl_xor(mx, 1));
                mx = fmaxf(mx, __shfl_xor(mx, 2));
                mx = fmaxf(mx, __shfl_xor(mx, 4));
                mx = fmaxf(mx, __shfl_xor(mx, 8));
                const float nm = fmaxf(m_r[reg], mx);
                const float a_ = __expf(m_r[reg] - nm);
                m_r[reg] = nm;
#pragma unroll
                for (int nt = 0; nt < 4; ++nt)
                    p_[nt][reg] = __expf(scr[nt] - nm);
                al[reg] = a_;
            }
#pragma unroll
            for (int nt = 0; nt < 4; ++nt)
#pragma unroll
                for (int reg = 0; reg < 4; ++reg) O[nt][reg] *= al[reg];

            // P: wave-private round-trip through EBuf's dead chunk-half (par cur)
            {
#pragma unroll
                for (int reg = 0; reg < 4; ++reg) {
                    ushort_t* pr = &EBuf[rw + reg][cur * 64];
                    pr[ 0 + lcol] = f2bf(p_[0][reg]);
                    pr[16 + lcol] = f2bf(p_[1][reg]);
                    pr[32 + lcol] = f2bf(p_[2][reg]);
                    pr[48 + lcol] = f2bf(p_[3][reg]);
                }
            }
            const short8 ap0 = *(const short8*)&EBuf[w * 16 + lcol][cur * 64 + quad * 8];
            const short8 ap1 = *(const short8*)&EBuf[w * 16 + lcol][cur * 64 + 32 + quad * 8];

            // row-sum of P via ones-MFMA (replaces the shfl sum tree)
            f32x4 lacc = {0, 0, 0, 0};
            lacc = MFMA(ap0, ones8, lacc, 0, 0, 0);
            lacc = MFMA(ap1, ones8, lacc, 0, 0, 0);
#pragma unroll
            for (int reg = 0; reg < 4; ++reg)
                l_r[reg] = l_r[reg] * al[reg] + lacc[reg];

            // PV: swizzled Vt[cur] fragment reads
            {
#pragma unroll
                for (int nt = 0; nt < 4; ++nt) {
                    const int hs = nt * 16 + lcol;
                    const int f = ((hs >> 3) & 7) ^ (hs & 7);
                    const short8 bv0 = *(const short8*)&Vt[cur][hs * 64 + ((quad ^ f) << 3)];
                    const short8 bv1 = *(const short8*)&Vt[cur][hs * 64 + (((4 + quad) ^ f) << 3)];
                    O[nt] = MFMA(ap0, bv0, O[nt], 0, 0, 0);
                    O[nt] = MFMA(ap1, bv1, O[nt], 0, 0, 0);
                }
            }
        }

        float inv[4];
#pragma unroll
        for (int reg = 0; reg < 4; ++reg) inv[reg] = 1.f / l_r[reg];
#pragma unroll
        for (int nt = 0; nt < 4; ++nt) {
#pragma unroll
            for (int reg = 0; reg < 4; ++reg) {
                const int r = w * 16 + quad * 4 + reg;
                y[(((size_t)bb * L_ + qi0 + r) * H_ + hh) * HS_ + nt * 16 + lcol] =
                    f2bf(O[nt][reg] * inv[reg]);
            }
        }
    }
}

// ---------------------------------------------------------------------------
extern "C" void kernel_launch(void* const* d_in, const int* in_sizes, int n_in,
                              void* d_out, int out_size, void* d_ws, size_t ws_size,
                              hipStream_t stream)
{
    const float* x      = (const float*)d_in[0];   // [B,L,D]
    const float* W_attn = (const float*)d_in[1];   // [D,3D]
    const float* b_attn = (const float*)d_in[2];   // [3D]
    const float* W_proj = (const float*)d_in[3];   // [D,D]
    const float* b_proj = (const float*)d_in[4];   // [D]
    const float* Er     = (const float*)d_in[5];   // [L,HS] fp32
    float* out = (float*)d_out;

    const size_t per = (size_t)B_ * H_ * L_ * HS_;   // 8388608
    ushort_t* qb  = (ushort_t*)d_ws;                 // bf16 q|k|v
    ushort_t* kb  = qb + per;
    ushort_t* vb  = kb + per;
    ushort_t* yb  = vb + per;                        // bf16 [B][L][D]
    ushort_t* xb  = yb + per;                        // bf16 x
    ushort_t* wat = xb + per;                        // W_attn^T bf16 [3072][1024]
    ushort_t* wpt = wat + (size_t)3 * D_ * D_;       // W_proj^T bf16 [1024][1024]
    ushort_t* erb = wpt + (size_t)D_ * D_;           // Er bf16 [L][HS]
    unsigned int* ctr = (unsigned int*)(erb + (size_t)L_ * HS_);  // work counter

    dim3 blk(256);

    conv_to_bf16<<<dim3((B_ * L_ * D_) / 2048), blk, 0, stream>>>(x, xb);
    conv_to_bf16<<<dim3((L_ * HS_) / 2048), blk, 0, stream>>>(Er, erb);
    zero_u32<<<dim3(1), dim3(1), 0, stream>>>(ctr);
    transpose_to_bf16<<<dim3(3 * D_ / 64, D_ / 64), blk, 0, stream>>>(W_attn, wat, D_, 3 * D_);
    transpose_to_bf16<<<dim3(D_ / 64, D_ / 64), blk, 0, stream>>>(W_proj, wpt, D_, D_);

    qkv_mfma<<<dim3(3 * D_ / 128, B_ * L_ / 128), blk, 0, stream>>>(xb, wat, b_attn, qb);

    attn_mfma<<<dim3(PERSIST), blk, 0, stream>>>(qb, kb, vb, erb, ctr, yb);

    proj_mfma<<<dim3(D_ / 128, B_ * L_ / 128), blk, 0, stream>>>(yb, wpt, b_proj, out);
}

// Round 11
// 410.116 us; speedup vs baseline: 1.1076x; 1.0300x over previous
//
#include <hip/hip_runtime.h>
#include <hip/hip_bf16.h>
#include <math.h>

#define B_  4
#define L_  2048
#define D_  1024
#define H_  16
#define HS_ 64
#define SCALE 0.125f   // 1/sqrt(64)

typedef unsigned short ushort_t;
typedef __attribute__((ext_vector_type(8))) short short8;
typedef __attribute__((ext_vector_type(4))) float f32x4;

#define MFMA __builtin_amdgcn_mfma_f32_16x16x32_bf16

static __device__ __forceinline__ ushort_t f2bf(float f) {
    union { float f; unsigned int u; } cv; cv.f = f;
    unsigned int u = cv.u;
    unsigned int r = (u + 0x7FFFu + ((u >> 16) & 1u)) >> 16;   // RNE
    return (ushort_t)r;
}
static __device__ __forceinline__ float bf2f(ushort_t h) {
    union { float f; unsigned int u; } cv; cv.u = ((unsigned int)h) << 16;
    return cv.f;
}

static __device__ __forceinline__ void gload_lds16(const ushort_t* g, ushort_t* l) {
    __builtin_amdgcn_global_load_lds(
        (const __attribute__((address_space(1))) unsigned int*)g,
        (__attribute__((address_space(3))) unsigned int*)l, 16, 0, 0);
}

// ---------------------------------------------------------------------------
// Prep: fused fp32->bf16 for x and Er + work-counter zero (one launch).
// ---------------------------------------------------------------------------
__global__ __launch_bounds__(256)
void conv_prep(const float* __restrict__ x, ushort_t* __restrict__ xb,
               const float* __restrict__ er, ushort_t* __restrict__ erb,
               unsigned int* __restrict__ ctr)
{
    if (blockIdx.x == 0 && threadIdx.x == 0) *ctr = 0u;
    const int xblocks = (B_ * L_ * D_) / 2048;
    const float4* src;
    ushort_t* dst;
    if ((int)blockIdx.x < xblocks) {
        const size_t i = (size_t)blockIdx.x * 256 + threadIdx.x;
        src = (const float4*)x + i * 2;
        dst = xb + i * 8;
    } else {
        const size_t i = (size_t)(blockIdx.x - xblocks) * 256 + threadIdx.x;
        src = (const float4*)er + i * 2;
        dst = erb + i * 8;
    }
    float4 a = src[0], b = src[1];
    ushort_t o[8] = {f2bf(a.x), f2bf(a.y), f2bf(a.z), f2bf(a.w),
                     f2bf(b.x), f2bf(b.y), f2bf(b.z), f2bf(b.w)};
    *(uint4*)dst = *(uint4*)o;
}

__global__ __launch_bounds__(256)
void transpose_to_bf16(const float* __restrict__ W, ushort_t* __restrict__ Wt,
                       int K, int N)   // W:[K][N] -> Wt:[N][K]
{
    __shared__ ushort_t tile[64][65];
    const int tid = threadIdx.x;
    const int n0 = blockIdx.x * 64, k0 = blockIdx.y * 64;
#pragma unroll
    for (int s = 0; s < 16; ++s) {
        const int idx = s * 256 + tid;
        const int kl = idx >> 6, nl = idx & 63;
        tile[nl][kl] = f2bf(W[(size_t)(k0 + kl) * N + n0 + nl]);
    }
    __syncthreads();
#pragma unroll
    for (int s = 0; s < 8; ++s) {
        const int idx = s * 256 + tid;
        const int nl = idx >> 5, kc = idx & 31;
        const unsigned int vlo = tile[nl][kc * 2];
        const unsigned int vhi = tile[nl][kc * 2 + 1];
        *(unsigned int*)(Wt + (size_t)(n0 + nl) * K + k0 + kc * 2) =
            vlo | (vhi << 16);
    }
}

// ---------------------------------------------------------------------------
// m97-style bf16 MFMA GEMM: C[M][N] = A[M][K] @ Bt[N][K]^T
// + XCD-bijective block swizzle (grids 1536/512, both %8==0) — validated R9.
// ---------------------------------------------------------------------------
__global__ __launch_bounds__(256)
void qkv_mfma(const ushort_t* __restrict__ A, const ushort_t* __restrict__ Bt,
              const float* __restrict__ bias, ushort_t* __restrict__ qkv)
{
    __shared__ __align__(16) ushort_t As[128 * 64];
    __shared__ __align__(16) ushort_t Bs[128 * 64];

    const int tid = threadIdx.x;
    const int w = tid >> 6, lane = tid & 63, quad = lane >> 4, lcol = lane & 15;
    const int wr = w >> 1, wc = w & 1;
    unsigned wg = blockIdx.y * gridDim.x + blockIdx.x;
    const unsigned nwg = gridDim.x * gridDim.y;
    wg = (wg & 7) * (nwg >> 3) + (wg >> 3);
    const int m0 = (int)(wg / gridDim.x) * 128;
    const int n0 = (int)(wg % gridDim.x) * 128;
    const int K = D_;

    const int srow = tid >> 3;
    const int cg = (tid & 7) ^ (srow & 7);
    const ushort_t* gA = A + (size_t)(m0 + srow) * K + cg * 8;
    const ushort_t* gB = Bt + (size_t)(n0 + srow) * K + cg * 8;
    ushort_t* lA = As + tid * 8;
    ushort_t* lB = Bs + tid * 8;

    const int cs0 = ((quad) ^ (lcol & 7)) * 8;
    const int cs1 = ((4 + quad) ^ (lcol & 7)) * 8;

    f32x4 acc[4][4];
#pragma unroll
    for (int i = 0; i < 4; ++i)
#pragma unroll
        for (int j = 0; j < 4; ++j) acc[i][j] = (f32x4){0, 0, 0, 0};

    for (int k0 = 0; k0 < K; k0 += 64) {
        __syncthreads();
#pragma unroll
        for (int s = 0; s < 4; ++s) {
            gload_lds16(gA + k0 + (size_t)s * 32 * K, lA + s * 2048);
            gload_lds16(gB + k0 + (size_t)s * 32 * K, lB + s * 2048);
        }
        __syncthreads();
#pragma unroll
        for (int kk = 0; kk < 2; ++kk) {
            const int cs = kk ? cs1 : cs0;
            short8 af[4], bf[4];
#pragma unroll
            for (int i = 0; i < 4; ++i)
                af[i] = *(const short8*)&As[(wr * 64 + i * 16 + lcol) * 64 + cs];
#pragma unroll
            for (int j = 0; j < 4; ++j)
                bf[j] = *(const short8*)&Bs[(wc * 64 + j * 16 + lcol) * 64 + cs];
#pragma unroll
            for (int i = 0; i < 4; ++i)
#pragma unroll
                for (int j = 0; j < 4; ++j)
                    acc[i][j] = MFMA(af[i], bf[j], acc[i][j], 0, 0, 0);
        }
    }

    const size_t per = (size_t)B_ * H_ * L_ * HS_;
#pragma unroll
    for (int j = 0; j < 4; ++j) {
        const int col = n0 + wc * 64 + j * 16 + lcol;
        const float bv = bias[col];
        const int sel = col >> 10;
        const int within = col & 1023;
        const int hh = within >> 6, hs = within & 63;
        ushort_t* base = qkv + (size_t)sel * per;
#pragma unroll
        for (int i = 0; i < 4; ++i) {
#pragma unroll
            for (int reg = 0; reg < 4; ++reg) {
                const int row = m0 + wr * 64 + i * 16 + quad * 4 + reg;
                const int bb = row >> 11, ll = row & 2047;
                base[(((size_t)(bb * H_ + hh)) * L_ + ll) * HS_ + hs] =
                    f2bf(acc[i][j][reg] + bv);
            }
        }
    }
}

__global__ __launch_bounds__(256)
void proj_mfma(const ushort_t* __restrict__ A, const ushort_t* __restrict__ Bt,
               const float* __restrict__ bias, float* __restrict__ C)
{
    __shared__ __align__(16) ushort_t As[128 * 64];
    __shared__ __align__(16) ushort_t Bs[128 * 64];

    const int tid = threadIdx.x;
    const int w = tid >> 6, lane = tid & 63, quad = lane >> 4, lcol = lane & 15;
    const int wr = w >> 1, wc = w & 1;
    unsigned wg = blockIdx.y * gridDim.x + blockIdx.x;
    const unsigned nwg = gridDim.x * gridDim.y;
    wg = (wg & 7) * (nwg >> 3) + (wg >> 3);
    const int m0 = (int)(wg / gridDim.x) * 128;
    const int n0 = (int)(wg % gridDim.x) * 128;
    const int K = D_;
    const int N = D_;

    const int srow = tid >> 3;
    const int cg = (tid & 7) ^ (srow & 7);
    const ushort_t* gA = A + (size_t)(m0 + srow) * K + cg * 8;
    const ushort_t* gB = Bt + (size_t)(n0 + srow) * K + cg * 8;
    ushort_t* lA = As + tid * 8;
    ushort_t* lB = Bs + tid * 8;

    const int cs0 = ((quad) ^ (lcol & 7)) * 8;
    const int cs1 = ((4 + quad) ^ (lcol & 7)) * 8;

    f32x4 acc[4][4];
#pragma unroll
    for (int i = 0; i < 4; ++i)
#pragma unroll
        for (int j = 0; j < 4; ++j) acc[i][j] = (f32x4){0, 0, 0, 0};

    for (int k0 = 0; k0 < K; k0 += 64) {
        __syncthreads();
#pragma unroll
        for (int s = 0; s < 4; ++s) {
            gload_lds16(gA + k0 + (size_t)s * 32 * K, lA + s * 2048);
            gload_lds16(gB + k0 + (size_t)s * 32 * K, lB + s * 2048);
        }
        __syncthreads();
#pragma unroll
        for (int kk = 0; kk < 2; ++kk) {
            const int cs = kk ? cs1 : cs0;
            short8 af[4], bf[4];
#pragma unroll
            for (int i = 0; i < 4; ++i)
                af[i] = *(const short8*)&As[(wr * 64 + i * 16 + lcol) * 64 + cs];
#pragma unroll
            for (int j = 0; j < 4; ++j)
                bf[j] = *(const short8*)&Bs[(wc * 64 + j * 16 + lcol) * 64 + cs];
#pragma unroll
            for (int i = 0; i < 4; ++i)
#pragma unroll
                for (int j = 0; j < 4; ++j)
                    acc[i][j] = MFMA(af[i], bf[j], acc[i][j], 0, 0, 0);
        }
    }

#pragma unroll
    for (int j = 0; j < 4; ++j) {
        const int col = n0 + wc * 64 + j * 16 + lcol;
        const float bv = bias[col];
#pragma unroll
        for (int i = 0; i < 4; ++i) {
#pragma unroll
            for (int reg = 0; reg < 4; ++reg) {
                const int row = m0 + wr * 64 + i * 16 + quad * 4 + reg;
                C[(size_t)row * N + col] = acc[i][j][reg] + bv;
            }
        }
    }
}

// ---------------------------------------------------------------------------
// MFMA flash attention, v12 = R10 (best: 267 us) + defer-max (T13, EXACT):
//  * Skip the 4-deep shfl max tree + al-exp + O-rescale when
//    __all(tile_max - m_r <= 8) — m_r frozen, P = exp(s - m_old) <= e^8
//    (bf16/f32 safe; same normalized result). After iter 0 this is the
//    ~always path; iter 0 (m_r=-inf -> NaN -> all()=false) takes the full
//    path, identical to R10.
//  * Everything else byte-identical to the validated R10 kernel.
// ---------------------------------------------------------------------------
#define QT 64
#define KT 64
#define NITEMS (B_ * H_ * (L_ / QT))   // 2048
#define PERSIST 768

__global__ __launch_bounds__(256, 3)
void attn_mfma(const ushort_t* __restrict__ q, const ushort_t* __restrict__ k,
               const ushort_t* __restrict__ v, const ushort_t* __restrict__ Erb,
               unsigned int* __restrict__ ctr, ushort_t* __restrict__ y)
{
    __shared__ __align__(16) ushort_t Kd[2][64 * 64];   // K tiles, swizzled
    __shared__ __align__(16) ushort_t Vt[2][64 * 64];   // [hs][key], swizzled
    __shared__ __align__(16) ushort_t EBuf[64][136];    // rolling QEr + P alias
    __shared__ int s_item;

    const int tid  = threadIdx.x;
    const int w    = tid >> 6;
    const int lane = tid & 63;
    const int quad = lane >> 4;
    const int lcol = lane & 15;
    const int rw   = w * 16 + quad * 4;

    // K async-staging constants (GEMM staging path)
    const int s_row = tid >> 3;                    // 0..31
    const int cgc   = (tid & 7) ^ (s_row & 7);     // swizzled source chunk
    // V transpose-staging constants: thread -> (key pair, hs block)
    const int vkp = (tid & 31) * 2;                // key pair base (even)
    const int vhb = (tid >> 5) * 8;                // hs block
    const int vkc = vkp >> 3, vks = vkp & 7;
    // fragment chunk offsets for Kd reads
    const int fs0 = ((quad) ^ (lcol & 7)) * 8;
    const int fs1 = ((4 + quad) ^ (lcol & 7)) * 8;

    const short8 ones8 = {(short)0x3F80, (short)0x3F80, (short)0x3F80, (short)0x3F80,
                          (short)0x3F80, (short)0x3F80, (short)0x3F80, (short)0x3F80};

    for (;;) {
        if (tid == 0) s_item = (int)atomicAdd(ctr, 1u);
        __syncthreads();                 // broadcast item; also fences LDS reuse
        const int idx = s_item;
        if (idx >= NITEMS) break;

        // decode: windows of 8 bh x 32 qt, heavy-first within window
        const int wnd = idx >> 8;                 // 0..7
        const int sub = idx & 255;
        const int qt  = 31 - (sub >> 3);
        const int bh  = wnd * 8 + (sub & 7);
        const int qi0 = qt * QT;
        const int bb  = bh >> 4;
        const int hh  = bh & 15;
        const int cband = L_ - QT - qi0;

        const ushort_t* qp = q + (size_t)bh * L_ * HS_;
        const ushort_t* kp = k + (size_t)bh * L_ * HS_;
        const ushort_t* vp = v + (size_t)bh * L_ * HS_;

        // Q fragments (one-time per item, direct from global)
        const ushort_t* qrow = qp + (size_t)(qi0 + w * 16 + lcol) * HS_;
        const short8 aq0 = *(const short8*)(qrow + quad * 8);
        const short8 aq1 = *(const short8*)(qrow + 32 + quad * 8);

        // ---- prologue ----
        // EBuf chunk 0 via direct-global Er MFMAs (one-time)
        {
            const ushort_t* eb = Erb + (size_t)cband * HS_;
            f32x4 e0 = {0,0,0,0}, e1 = {0,0,0,0}, e2 = {0,0,0,0}, e3 = {0,0,0,0};
            e0 = MFMA(aq0, *(const short8*)(eb + (size_t)( 0 + lcol) * HS_ +      quad * 8), e0, 0,0,0);
            e1 = MFMA(aq0, *(const short8*)(eb + (size_t)(16 + lcol) * HS_ +      quad * 8), e1, 0,0,0);
            e2 = MFMA(aq0, *(const short8*)(eb + (size_t)(32 + lcol) * HS_ +      quad * 8), e2, 0,0,0);
            e3 = MFMA(aq0, *(const short8*)(eb + (size_t)(48 + lcol) * HS_ +      quad * 8), e3, 0,0,0);
            e0 = MFMA(aq1, *(const short8*)(eb + (size_t)( 0 + lcol) * HS_ + 32 + quad * 8), e0, 0,0,0);
            e1 = MFMA(aq1, *(const short8*)(eb + (size_t)(16 + lcol) * HS_ + 32 + quad * 8), e1, 0,0,0);
            e2 = MFMA(aq1, *(const short8*)(eb + (size_t)(32 + lcol) * HS_ + 32 + quad * 8), e2, 0,0,0);
            e3 = MFMA(aq1, *(const short8*)(eb + (size_t)(48 + lcol) * HS_ + 32 + quad * 8), e3, 0,0,0);
#pragma unroll
            for (int reg = 0; reg < 4; ++reg) {
                EBuf[rw + reg][ 0 + lcol] = f2bf(e0[reg]);
                EBuf[rw + reg][16 + lcol] = f2bf(e1[reg]);
                EBuf[rw + reg][32 + lcol] = f2bf(e2[reg]);
                EBuf[rw + reg][48 + lcol] = f2bf(e3[reg]);
            }
        }
        // stage K tile 0 -> Kd[0]
        {
            const ushort_t* g = kp + (size_t)s_row * HS_ + cgc * 8;
            gload_lds16(g,            &Kd[0][tid * 8]);
            gload_lds16(g + 32 * HS_, &Kd[0][2048 + tid * 8]);
        }
        // Er fragments for chunk 1 -> regs (row-clamped)
        short8 erf[8];
#pragma unroll
        for (int nt = 0; nt < 4; ++nt) {
            int r = cband + 64 + nt * 16 + lcol;
            if (r > L_ - 1) r = L_ - 1;
            const ushort_t* p = Erb + (size_t)r * HS_ + quad * 8;
            erf[nt * 2]     = *(const short8*)p;
            erf[nt * 2 + 1] = *(const short8*)(p + 32);
        }
        // V tile 0 -> Vt[0] (sync reg round-trip, packed b32 swizzled write)
        {
            const ushort_t* src = vp + (size_t)vkp * HS_ + vhb;
            uint4 a = *(const uint4*)src;
            uint4 b = *(const uint4*)(src + HS_);
            const ushort_t* pa = (const ushort_t*)&a;
            const ushort_t* pb = (const ushort_t*)&b;
#pragma unroll
            for (int u = 0; u < 8; ++u) {
                const int hs = vhb + u;
                const int f = ((hs >> 3) & 7) ^ (hs & 7);
                const unsigned int val = (unsigned int)pa[u] | ((unsigned int)pb[u] << 16);
                *(unsigned int*)&Vt[0][hs * 64 + ((vkc ^ f) << 3) + vks] = val;
            }
        }
        // V tile 1 -> regs (unused if qt==0; rows always in-bounds)
        uint4 va, vb;
        {
            const ushort_t* src = vp + (size_t)(KT + vkp) * HS_ + vhb;
            va = *(const uint4*)src; vb = *(const uint4*)(src + HS_);
        }

        f32x4 O[4];
#pragma unroll
        for (int nt = 0; nt < 4; ++nt) O[nt] = (f32x4){0, 0, 0, 0};
        float m_r[4] = {-INFINITY, -INFINITY, -INFINITY, -INFINITY};
        float l_r[4] = {0, 0, 0, 0};

        for (int kt = 0; kt <= qt; ++kt) {
            const int kj0 = kt * KT;
            const int cur = kt & 1, nxt = cur ^ 1;

            __syncthreads();   // drains last iter's async stages; orders buffers

            if (kt < qt) {
                // write Vt[nxt] <- V tile kt+1 (regs loaded last iter)
                {
                    const ushort_t* pa = (const ushort_t*)&va;
                    const ushort_t* pb = (const ushort_t*)&vb;
#pragma unroll
                    for (int u = 0; u < 8; ++u) {
                        const int hs = vhb + u;
                        const int f = ((hs >> 3) & 7) ^ (hs & 7);
                        const unsigned int val = (unsigned int)pa[u] | ((unsigned int)pb[u] << 16);
                        *(unsigned int*)&Vt[nxt][hs * 64 + ((vkc ^ f) << 3) + vks] = val;
                    }
                }
                // issue V tile kt+2 -> regs (row-clamped)
                {
                    int kj2 = (kt + 2) * KT;
                    if (kj2 > L_ - KT) kj2 = L_ - KT;
                    const ushort_t* src = vp + (size_t)(kj2 + vkp) * HS_ + vhb;
                    va = *(const uint4*)src; vb = *(const uint4*)(src + HS_);
                }
                // issue K tile kt+1 -> Kd[nxt]
                {
                    const ushort_t* g = kp + (size_t)((kt + 1) * KT + s_row) * HS_ + cgc * 8;
                    gload_lds16(g,            &Kd[nxt][tid * 8]);
                    gload_lds16(g + 32 * HS_, &Kd[nxt][2048 + tid * 8]);
                }
            }

            // ---- QEr chunk kt+1 from erf regs ----
            f32x4 e0 = {0,0,0,0}, e1 = {0,0,0,0}, e2 = {0,0,0,0}, e3 = {0,0,0,0};
            e0 = MFMA(aq0, erf[0], e0, 0,0,0);
            e1 = MFMA(aq0, erf[2], e1, 0,0,0);
            e2 = MFMA(aq0, erf[4], e2, 0,0,0);
            e3 = MFMA(aq0, erf[6], e3, 0,0,0);
            e0 = MFMA(aq1, erf[1], e0, 0,0,0);
            e1 = MFMA(aq1, erf[3], e1, 0,0,0);
            e2 = MFMA(aq1, erf[5], e2, 0,0,0);
            e3 = MFMA(aq1, erf[7], e3, 0,0,0);

            // reload erf <- Er fragments for chunk kt+2 (WAR; lands next iter)
            {
                const int ebase = cband + (kt + 2) * 64;
#pragma unroll
                for (int nt = 0; nt < 4; ++nt) {
                    int r = ebase + nt * 16 + lcol;
                    if (r > L_ - 1) r = L_ - 1;
                    const ushort_t* p = Erb + (size_t)r * HS_ + quad * 8;
                    erf[nt * 2]     = *(const short8*)p;
                    erf[nt * 2 + 1] = *(const short8*)(p + 32);
                }
            }

            {
                const int par = nxt * 64;   // chunk kt+1
#pragma unroll
                for (int reg = 0; reg < 4; ++reg) {
                    EBuf[rw + reg][par +  0 + lcol] = f2bf(e0[reg]);
                    EBuf[rw + reg][par + 16 + lcol] = f2bf(e1[reg]);
                    EBuf[rw + reg][par + 32 + lcol] = f2bf(e2[reg]);
                    EBuf[rw + reg][par + 48 + lcol] = f2bf(e3[reg]);
                }
            }

            // ---- scores from Kd[cur] ----
            f32x4 s0 = {0,0,0,0}, s1 = {0,0,0,0}, s2 = {0,0,0,0}, s3 = {0,0,0,0};
            s0 = MFMA(aq0, *(const short8*)&Kd[cur][( 0 + lcol) * 64 + fs0], s0, 0,0,0);
            s1 = MFMA(aq0, *(const short8*)&Kd[cur][(16 + lcol) * 64 + fs0], s1, 0,0,0);
            s2 = MFMA(aq0, *(const short8*)&Kd[cur][(32 + lcol) * 64 + fs0], s2, 0,0,0);
            s3 = MFMA(aq0, *(const short8*)&Kd[cur][(48 + lcol) * 64 + fs0], s3, 0,0,0);
            s0 = MFMA(aq1, *(const short8*)&Kd[cur][( 0 + lcol) * 64 + fs1], s0, 0,0,0);
            s1 = MFMA(aq1, *(const short8*)&Kd[cur][(16 + lcol) * 64 + fs1], s1, 0,0,0);
            s2 = MFMA(aq1, *(const short8*)&Kd[cur][(32 + lcol) * 64 + fs1], s2, 0,0,0);
            s3 = MFMA(aq1, *(const short8*)&Kd[cur][(48 + lcol) * 64 + fs1], s3, 0,0,0);

            float p_[4][4];      // raw scores, then P
            float al[4] = {1.f, 1.f, 1.f, 1.f};
            float mxl[4];
            const float sq[4][4] = {
                {s0[0], s0[1], s0[2], s0[3]},
                {s1[0], s1[1], s1[2], s1[3]},
                {s2[0], s2[1], s2[2], s2[3]},
                {s3[0], s3[1], s3[2], s3[3]}};
#pragma unroll
            for (int reg = 0; reg < 4; ++reg) {
                const int r = w * 16 + quad * 4 + reg;
#pragma unroll
                for (int nt = 0; nt < 4; ++nt) {
                    const int jl = nt * 16 + lcol;
                    const int c = (63 - r + jl + kj0) & 127;
                    float sv = (sq[nt][reg] + bf2f(EBuf[r][c])) * SCALE;
                    if (kt == qt && jl > r) sv = -INFINITY;
                    p_[nt][reg] = sv;
                }
                mxl[reg] = fmaxf(fmaxf(p_[0][reg], p_[1][reg]),
                                 fmaxf(p_[2][reg], p_[3][reg]));
            }
            const float dmax = fmaxf(fmaxf(mxl[0] - m_r[0], mxl[1] - m_r[1]),
                                     fmaxf(mxl[2] - m_r[2], mxl[3] - m_r[3]));
            if (__all(dmax <= 8.0f)) {
                // defer: m_r frozen, al=1, no shfl tree, no O rescale (EXACT)
#pragma unroll
                for (int reg = 0; reg < 4; ++reg)
#pragma unroll
                    for (int nt = 0; nt < 4; ++nt)
                        p_[nt][reg] = __expf(p_[nt][reg] - m_r[reg]);
            } else {
#pragma unroll
                for (int reg = 0; reg < 4; ++reg) {
                    float mx = mxl[reg];
                    mx = fmaxf(mx, __shfl_xor(mx, 1));
                    mx = fmaxf(mx, __shfl_xor(mx, 2));
                    mx = fmaxf(mx, __shfl_xor(mx, 4));
                    mx = fmaxf(mx, __shfl_xor(mx, 8));
                    const float nm = fmaxf(m_r[reg], mx);
                    al[reg] = __expf(m_r[reg] - nm);
                    m_r[reg] = nm;
#pragma unroll
                    for (int nt = 0; nt < 4; ++nt)
                        p_[nt][reg] = __expf(p_[nt][reg] - nm);
                }
#pragma unroll
                for (int nt = 0; nt < 4; ++nt)
#pragma unroll
                    for (int reg = 0; reg < 4; ++reg) O[nt][reg] *= al[reg];
            }

            // P: wave-private round-trip through EBuf's dead chunk-half (par cur)
            {
#pragma unroll
                for (int reg = 0; reg < 4; ++reg) {
                    ushort_t* pr = &EBuf[rw + reg][cur * 64];
                    pr[ 0 + lcol] = f2bf(p_[0][reg]);
                    pr[16 + lcol] = f2bf(p_[1][reg]);
                    pr[32 + lcol] = f2bf(p_[2][reg]);
                    pr[48 + lcol] = f2bf(p_[3][reg]);
                }
            }
            const short8 ap0 = *(const short8*)&EBuf[w * 16 + lcol][cur * 64 + quad * 8];
            const short8 ap1 = *(const short8*)&EBuf[w * 16 + lcol][cur * 64 + 32 + quad * 8];

            // row-sum of P via ones-MFMA (replaces the shfl sum tree)
            f32x4 lacc = {0, 0, 0, 0};
            lacc = MFMA(ap0, ones8, lacc, 0, 0, 0);
            lacc = MFMA(ap1, ones8, lacc, 0, 0, 0);
#pragma unroll
            for (int reg = 0; reg < 4; ++reg)
                l_r[reg] = l_r[reg] * al[reg] + lacc[reg];

            // PV: swizzled Vt[cur] fragment reads
            {
#pragma unroll
                for (int nt = 0; nt < 4; ++nt) {
                    const int hs = nt * 16 + lcol;
                    const int f = ((hs >> 3) & 7) ^ (hs & 7);
                    const short8 bv0 = *(const short8*)&Vt[cur][hs * 64 + ((quad ^ f) << 3)];
                    const short8 bv1 = *(const short8*)&Vt[cur][hs * 64 + (((4 + quad) ^ f) << 3)];
                    O[nt] = MFMA(ap0, bv0, O[nt], 0, 0, 0);
                    O[nt] = MFMA(ap1, bv1, O[nt], 0, 0, 0);
                }
            }
        }

        float inv[4];
#pragma unroll
        for (int reg = 0; reg < 4; ++reg) inv[reg] = 1.f / l_r[reg];
#pragma unroll
        for (int nt = 0; nt < 4; ++nt) {
#pragma unroll
            for (int reg = 0; reg < 4; ++reg) {
                const int r = w * 16 + quad * 4 + reg;
                y[(((size_t)bb * L_ + qi0 + r) * H_ + hh) * HS_ + nt * 16 + lcol] =
                    f2bf(O[nt][reg] * inv[reg]);
            }
        }
    }
}

// ---------------------------------------------------------------------------
extern "C" void kernel_launch(void* const* d_in, const int* in_sizes, int n_in,
                              void* d_out, int out_size, void* d_ws, size_t ws_size,
                              hipStream_t stream)
{
    const float* x      = (const float*)d_in[0];   // [B,L,D]
    const float* W_attn = (const float*)d_in[1];   // [D,3D]
    const float* b_attn = (const float*)d_in[2];   // [3D]
    const float* W_proj = (const float*)d_in[3];   // [D,D]
    const float* b_proj = (const float*)d_in[4];   // [D]
    const float* Er     = (const float*)d_in[5];   // [L,HS] fp32
    float* out = (float*)d_out;

    const size_t per = (size_t)B_ * H_ * L_ * HS_;   // 8388608
    ushort_t* qb  = (ushort_t*)d_ws;                 // bf16 q|k|v
    ushort_t* kb  = qb + per;
    ushort_t* vb  = kb + per;
    ushort_t* yb  = vb + per;                        // bf16 [B][L][D]
    ushort_t* xb  = yb + per;                        // bf16 x
    ushort_t* wat = xb + per;                        // W_attn^T bf16 [3072][1024]
    ushort_t* wpt = wat + (size_t)3 * D_ * D_;       // W_proj^T bf16 [1024][1024]
    ushort_t* erb = wpt + (size_t)D_ * D_;           // Er bf16 [L][HS]
    unsigned int* ctr = (unsigned int*)(erb + (size_t)L_ * HS_);  // work counter

    dim3 blk(256);

    const int xblocks = (B_ * L_ * D_) / 2048;       // 4096
    const int eblocks = (L_ * HS_) / 2048;           // 64
    conv_prep<<<dim3(xblocks + eblocks), blk, 0, stream>>>(x, xb, Er, erb, ctr);
    transpose_to_bf16<<<dim3(3 * D_ / 64, D_ / 64), blk, 0, stream>>>(W_attn, wat, D_, 3 * D_);
    transpose_to_bf16<<<dim3(D_ / 64, D_ / 64), blk, 0, stream>>>(W_proj, wpt, D_, D_);

    qkv_mfma<<<dim3(3 * D_ / 128, B_ * L_ / 128), blk, 0, stream>>>(xb, wat, b_attn, qb);

    attn_mfma<<<dim3(PERSIST), blk, 0, stream>>>(qb, kb, vb, erb, ctr, yb);

    proj_mfma<<<dim3(D_ / 128, B_ * L_ / 128), blk, 0, stream>>>(yb, wpt, b_proj, out);
}